// Round 1
// baseline (110.484 us; speedup 1.0000x reference)
//
#include <hip/hip_runtime.h>

// rfft512 over 32768 rows.
// One wave (64 lanes) per row. z[n] = x[2n] + i*x[2n+1] -> FFT_256 (Stockham
// radix-4 DIF, 4 stages, LDS ping-pong) -> rfft untangle -> bins 0..256.

#define NFFT 512
#define MC   256
#define WPB  4                      // waves (=rows) per 256-thread block
#define PAD(i) ((i) + ((i) >> 5))   // LDS padding: breaks power-of-2 write strides

// One Stockham radix-4 DIF stage (OTFFT formulation):
//   reads  src[t + {0,64,128,192}]          (t = lane)
//   writes dst[wbase + {0,ws,2ws,3ws}]
//   twiddle w1 = exp(-2*pi*i * p / n), w2 = w1^2, w3 = w1^3
__device__ __forceinline__ void r4stage(
    const float* __restrict__ sr, const float* __restrict__ si,
    float* __restrict__ dr, float* __restrict__ di,
    int t, int p, int wbase, int ws, float invn)
{
    float ar = sr[PAD(t)],       ai = si[PAD(t)];
    float br = sr[PAD(t + 64)],  bi = si[PAD(t + 64)];
    float cr = sr[PAD(t + 128)], ci = si[PAD(t + 128)];
    float er = sr[PAD(t + 192)], ei = si[PAD(t + 192)];

    float apcr = ar + cr, apci = ai + ci;
    float amcr = ar - cr, amci = ai - ci;
    float bpdr = br + er, bpdi = bi + ei;
    float bmdr = br - er, bmdi = bi - ei;

    float y0r = apcr + bpdr, y0i = apci + bpdi;
    float u1r = amcr + bmdi, u1i = amci - bmdr;   // amc - i*bmd
    float u2r = apcr - bpdr, u2i = apci - bpdi;   // apc - bpd
    float u3r = amcr - bmdi, u3i = amci + bmdr;   // amc + i*bmd

    float ang = -6.28318530717958647692f * (float)p * invn;
    float sn, cs;
    __sincosf(ang, &sn, &cs);
    float w1r = cs, w1i = sn;
    float w2r = cs * cs - sn * sn, w2i = 2.0f * cs * sn;
    float w3r = w1r * w2r - w1i * w2i, w3i = w1r * w2i + w1i * w2r;

    dr[PAD(wbase)]          = y0r;
    di[PAD(wbase)]          = y0i;
    dr[PAD(wbase + ws)]     = w1r * u1r - w1i * u1i;
    di[PAD(wbase + ws)]     = w1r * u1i + w1i * u1r;
    dr[PAD(wbase + 2 * ws)] = w2r * u2r - w2i * u2i;
    di[PAD(wbase + 2 * ws)] = w2r * u2i + w2i * u2r;
    dr[PAD(wbase + 3 * ws)] = w3r * u3r - w3i * u3i;
    di[PAD(wbase + 3 * ws)] = w3r * u3i + w3i * u3r;
}

__global__ __launch_bounds__(256) void rfft512_kernel(
    const float* __restrict__ x, float* __restrict__ out, int batch)
{
    __shared__ float lds[WPB][4][264];   // per wave: re0, im0, re1, im1
    const int t = threadIdx.x & 63;
    const int w = threadIdx.x >> 6;
    long long b = (long long)blockIdx.x * WPB + w;
    if (b >= batch) b = batch - 1;       // clamp (duplicate work, always safe)

    float* re0 = lds[w][0];
    float* im0 = lds[w][1];
    float* re1 = lds[w][2];
    float* im1 = lds[w][3];

    // Load 512 reals as 256 complex: float4 gives (z[2t].re, z[2t].im, z[2t+1].re, z[2t+1].im)
    const float4* xf4 = (const float4*)(x + b * NFFT);
    float4 v0 = xf4[t];
    float4 v1 = xf4[t + 64];
    re0[PAD(2 * t)]       = v0.x;  im0[PAD(2 * t)]       = v0.y;
    re0[PAD(2 * t + 1)]   = v0.z;  im0[PAD(2 * t + 1)]   = v0.w;
    re0[PAD(2 * t + 128)] = v1.x;  im0[PAD(2 * t + 128)] = v1.y;
    re0[PAD(2 * t + 129)] = v1.z;  im0[PAD(2 * t + 129)] = v1.w;
    __syncthreads();

    // FFT_256: 4 Stockham radix-4 stages, natural order in & out.
    // Stage A: n=256, s=1  : p=t,    wbase=4t,              ws=1
    r4stage(re0, im0, re1, im1, t, t, 4 * t, 1, 1.0f / 256.0f);
    __syncthreads();
    // Stage B: n=64,  s=4  : p=t>>2, wbase=(t&3)+16*(t>>2), ws=4
    r4stage(re1, im1, re0, im0, t, t >> 2, (t & 3) + 16 * (t >> 2), 4, 1.0f / 64.0f);
    __syncthreads();
    // Stage C: n=16,  s=16 : p=t>>4, wbase=(t&15)+64*(t>>4), ws=16
    r4stage(re0, im0, re1, im1, t, t >> 4, (t & 15) + 64 * (t >> 4), 16, 1.0f / 16.0f);
    __syncthreads();
    // Stage D: n=4,   s=64 : p=0 (twiddles = 1), wbase=t,   ws=64
    r4stage(re1, im1, re0, im0, t, 0, t, 64, 1.0f / 4.0f);
    __syncthreads();

    // rfft untangle: X[k] = A + exp(-2*pi*i*k/512) * B,
    //   A = (Z[k] + conj(Z[M-k]))/2,  B = (Z[k] - conj(Z[M-k]))/(2i)
    float* outRe = out + b * 257;
    float* outIm = out + (long long)batch * 257 + b * 257;
#pragma unroll
    for (int j = 0; j < 4; ++j) {
        int k = t + 64 * j;
        int km = (MC - k) & (MC - 1);
        float zr = re0[PAD(k)],  zi = im0[PAD(k)];
        float pr = re0[PAD(km)], pi = im0[PAD(km)];
        float Ar = 0.5f * (zr + pr);
        float Ai = 0.5f * (zi - pi);
        float Br = 0.5f * (zi + pi);
        float Bi = -0.5f * (zr - pr);
        float ang = -6.28318530717958647692f * (float)k * (1.0f / 512.0f);
        float sn, cs;
        __sincosf(ang, &sn, &cs);
        outRe[k] = Ar + cs * Br - sn * Bi;
        outIm[k] = Ai + cs * Bi + sn * Br;
    }
    if (t == 0) {
        // k = 256: X[256] = Re(Z[0]) - Im(Z[0]), imag exactly 0
        float zr = re0[PAD(0)], zi = im0[PAD(0)];
        outRe[256] = zr - zi;
        outIm[256] = 0.0f;
    }
}

extern "C" void kernel_launch(void* const* d_in, const int* in_sizes, int n_in,
                              void* d_out, int out_size, void* d_ws, size_t ws_size,
                              hipStream_t stream)
{
    const float* x = (const float*)d_in[0];
    float* out = (float*)d_out;
    const int batch = in_sizes[0] / NFFT;           // 32768
    const int grid = (batch + WPB - 1) / WPB;       // 8192 blocks of 256
    rfft512_kernel<<<grid, 256, 0, stream>>>(x, out, batch);
}

// Round 2
// 109.073 us; speedup vs baseline: 1.0129x; 1.0129x over previous
//
#include <hip/hip_runtime.h>

// rfft512 over 32768 rows, one wave64 per row.
// z[n] = x[2n] + i*x[2n+1] -> FFT_256 (Stockham radix-4 DIF, 4 stages,
// float2 LDS ping-pong, XOR-swizzled banks) -> rfft untangle -> bins 0..256.
//
// Wave-synchronous: each row is owned by exactly one wave, so stage
// boundaries need only "s_waitcnt lgkmcnt(0)" (wave64 is lockstep), no
// __syncthreads. XOR swizzle phys(i)=i^((i>>2)&12) makes all stage
// read/write patterns bank-conflict-free while preserving contiguity of
// stage-A's 4-consecutive-complex writes (float4-able).

#define NFFT 512
#define WPB  4   // waves (=rows) per 256-thread block

__device__ __forceinline__ int SW(int i) { return i ^ ((i >> 2) & 12); }

__device__ __forceinline__ void waveSyncLds() {
    asm volatile("s_waitcnt lgkmcnt(0)" ::: "memory");
}

__global__ __launch_bounds__(256) void rfft512_kernel(
    const float* __restrict__ x, float* __restrict__ out, int batch)
{
    __shared__ __align__(16) float2 lds[WPB][2][256];
    const int t = threadIdx.x & 63;
    const int w = threadIdx.x >> 6;
    long long b = (long long)blockIdx.x * WPB + w;
    if (b >= batch) b = batch - 1;   // safe clamp (grid divides exactly anyway)

    float2* buf0 = lds[w][0];
    float2* buf1 = lds[w][1];

    // ---- Load: 512 reals = 256 complex. Lane t owns z[2t],z[2t+1] and
    // z[2t+128],z[2t+129]; both pairs stay contiguous under SW -> float4.
    const float4* xf4 = (const float4*)(x + b * NFFT);
    float4 v0 = xf4[t];
    float4 v1 = xf4[t + 64];
    {
        int p0 = SW(2 * t);                    // even; SW(2t+128) = p0+128
        float4* b4 = (float4*)buf0;
        b4[p0 >> 1]        = v0;
        b4[(p0 >> 1) + 64] = v1;
    }
    waveSyncLds();

    const float NEG2PI = -6.28318530717958647692f;

    // ---- Stage A: n=256, s=1 : p=t, wbase=4t, ws=1 (contiguous writes)
    {
        int rb = SW(t);
        float2 a = buf0[rb], bb = buf0[rb + 64], c = buf0[rb + 128], d = buf0[rb + 192];
        float apcr = a.x + c.x, apci = a.y + c.y;
        float amcr = a.x - c.x, amci = a.y - c.y;
        float bpdr = bb.x + d.x, bpdi = bb.y + d.y;
        float bmdr = bb.x - d.x, bmdi = bb.y - d.y;
        float y0r = apcr + bpdr, y0i = apci + bpdi;
        float u1r = amcr + bmdi, u1i = amci - bmdr;
        float u2r = apcr - bpdr, u2i = apci - bpdi;
        float u3r = amcr - bmdi, u3i = amci + bmdr;
        float sn, cs;
        __sincosf(NEG2PI * (float)t * (1.0f / 256.0f), &sn, &cs);
        float w1r = cs, w1i = sn;
        float w2r = cs * cs - sn * sn, w2i = 2.0f * cs * sn;
        float w3r = w1r * w2r - w1i * w2i, w3i = w1r * w2i + w1i * w2r;
        int wb = (4 * t) ^ (t & 12);           // SW(4t), multiple of 4
        float4* d4 = (float4*)buf1;
        d4[wb >> 1]       = make_float4(y0r, y0i,
                                        w1r * u1r - w1i * u1i, w1r * u1i + w1i * u1r);
        d4[(wb >> 1) + 1] = make_float4(w2r * u2r - w2i * u2i, w2r * u2i + w2i * u2r,
                                        w3r * u3r - w3i * u3i, w3r * u3i + w3i * u3r);
    }
    waveSyncLds();

    // ---- Stage B: n=64, s=4 : p=t>>2, wbase=(t&3)+16*(t>>2), ws=4
    {
        int rb = SW(t);
        float2 a = buf1[rb], bb = buf1[rb + 64], c = buf1[rb + 128], d = buf1[rb + 192];
        float apcr = a.x + c.x, apci = a.y + c.y;
        float amcr = a.x - c.x, amci = a.y - c.y;
        float bpdr = bb.x + d.x, bpdi = bb.y + d.y;
        float bmdr = bb.x - d.x, bmdi = bb.y - d.y;
        float y0r = apcr + bpdr, y0i = apci + bpdi;
        float u1r = amcr + bmdi, u1i = amci - bmdr;
        float u2r = apcr - bpdr, u2i = apci - bpdi;
        float u3r = amcr - bmdi, u3i = amci + bmdr;
        float sn, cs;
        __sincosf(NEG2PI * (float)(t >> 2) * (1.0f / 64.0f), &sn, &cs);
        float w1r = cs, w1i = sn;
        float w2r = cs * cs - sn * sn, w2i = 2.0f * cs * sn;
        float w3r = w1r * w2r - w1i * w2i, w3i = w1r * w2i + w1i * w2r;
        int wbase = (t & 3) + 16 * (t >> 2);
        buf0[SW(wbase)]      = make_float2(y0r, y0i);
        buf0[SW(wbase + 4)]  = make_float2(w1r * u1r - w1i * u1i, w1r * u1i + w1i * u1r);
        buf0[SW(wbase + 8)]  = make_float2(w2r * u2r - w2i * u2i, w2r * u2i + w2i * u2r);
        buf0[SW(wbase + 12)] = make_float2(w3r * u3r - w3i * u3i, w3r * u3i + w3i * u3r);
    }
    waveSyncLds();

    // ---- Stage C: n=16, s=16 : p=t>>4, wbase=(t&15)+64*(t>>4), ws=16
    {
        int rb = SW(t);
        float2 a = buf0[rb], bb = buf0[rb + 64], c = buf0[rb + 128], d = buf0[rb + 192];
        float apcr = a.x + c.x, apci = a.y + c.y;
        float amcr = a.x - c.x, amci = a.y - c.y;
        float bpdr = bb.x + d.x, bpdi = bb.y + d.y;
        float bmdr = bb.x - d.x, bmdi = bb.y - d.y;
        float y0r = apcr + bpdr, y0i = apci + bpdi;
        float u1r = amcr + bmdi, u1i = amci - bmdr;
        float u2r = apcr - bpdr, u2i = apci - bpdi;
        float u3r = amcr - bmdi, u3i = amci + bmdr;
        float sn, cs;
        __sincosf(NEG2PI * (float)(t >> 4) * (1.0f / 16.0f), &sn, &cs);
        float w1r = cs, w1i = sn;
        float w2r = cs * cs - sn * sn, w2i = 2.0f * cs * sn;
        float w3r = w1r * w2r - w1i * w2i, w3i = w1r * w2i + w1i * w2r;
        int wbase = (t & 15) + 64 * (t >> 4);
        buf1[SW(wbase)]      = make_float2(y0r, y0i);
        buf1[SW(wbase + 16)] = make_float2(w1r * u1r - w1i * u1i, w1r * u1i + w1i * u1r);
        buf1[SW(wbase + 32)] = make_float2(w2r * u2r - w2i * u2i, w2r * u2i + w2i * u2r);
        buf1[SW(wbase + 48)] = make_float2(w3r * u3r - w3i * u3i, w3r * u3i + w3i * u3r);
    }
    waveSyncLds();

    // ---- Stage D: n=4, s=64 : p=0 (unit twiddles), wbase=t, ws=64.
    // Lane-local: read offsets == write offsets. Keep results (k = t+64j)
    // in registers; write to LDS only for the untangle partner gather.
    float zr[4], zi[4];
    {
        int rb = SW(t);
        float2 a = buf1[rb], bb = buf1[rb + 64], c = buf1[rb + 128], d = buf1[rb + 192];
        float apcr = a.x + c.x, apci = a.y + c.y;
        float amcr = a.x - c.x, amci = a.y - c.y;
        float bpdr = bb.x + d.x, bpdi = bb.y + d.y;
        float bmdr = bb.x - d.x, bmdi = bb.y - d.y;
        zr[0] = apcr + bpdr; zi[0] = apci + bpdi;
        zr[1] = amcr + bmdi; zi[1] = amci - bmdr;
        zr[2] = apcr - bpdr; zi[2] = apci - bpdi;
        zr[3] = amcr - bmdi; zi[3] = amci + bmdr;
        buf0[rb]       = make_float2(zr[0], zi[0]);
        buf0[rb + 64]  = make_float2(zr[1], zi[1]);
        buf0[rb + 128] = make_float2(zr[2], zi[2]);
        buf0[rb + 192] = make_float2(zr[3], zi[3]);
    }
    waveSyncLds();

    // ---- rfft untangle: X[k] = A + exp(-2*pi*i*k/512)*B, k = t+64j
    float* outRe = out + b * 257;
    float* outIm = out + (long long)batch * 257 + b * 257;
#pragma unroll
    for (int j = 0; j < 4; ++j) {
        int k = t + 64 * j;
        int km = (256 - k) & 255;
        float2 pm = buf0[SW(km)];
        float Ar = 0.5f * (zr[j] + pm.x);
        float Ai = 0.5f * (zi[j] - pm.y);
        float Br = 0.5f * (zi[j] + pm.y);
        float Bi = -0.5f * (zr[j] - pm.x);
        float sn, cs;
        __sincosf(NEG2PI * (float)k * (1.0f / 512.0f), &sn, &cs);
        outRe[k] = Ar + cs * Br - sn * Bi;
        outIm[k] = Ai + cs * Bi + sn * Br;
    }
    if (t == 0) {
        outRe[256] = zr[0] - zi[0];   // X[256] = Re(Z[0]) - Im(Z[0])
        outIm[256] = 0.0f;
    }
}

extern "C" void kernel_launch(void* const* d_in, const int* in_sizes, int n_in,
                              void* d_out, int out_size, void* d_ws, size_t ws_size,
                              hipStream_t stream)
{
    const float* x = (const float*)d_in[0];
    float* out = (float*)d_out;
    const int batch = in_sizes[0] / NFFT;        // 32768
    const int grid = (batch + WPB - 1) / WPB;    // 8192 blocks of 256
    rfft512_kernel<<<grid, 256, 0, stream>>>(x, out, batch);
}